// Round 3
// baseline (164.830 us; speedup 1.0000x reference)
//
#include <hip/hip_runtime.h>
#include <stdint.h>

#define N_ANCHORS 6144
#define NUM_CLASSES 80
#define NWORDS 96   // 6144 / 64
#define NTILES 24   // 6144 / 256

// ---------------- static device scratch (avoids ws_size assumptions) ----------------
__device__ unsigned long long g_mask[(size_t)N_ANCHORS * NWORDS]; // suppression bitmask rows (sorted space)
__device__ float4 g_sbox[N_ANCHORS];     // sorted boxes
__device__ int    g_rpart[NTILES][N_ANCHORS]; // per-j-tile rank partials
__device__ int    g_fpart[NTILES][N_ANCHORS]; // per-j-tile filtered-index partials
__device__ int    g_sAnchor[N_ANCHORS];  // sorted pos -> anchor id
__device__ int    g_sFi[N_ANCHORS];      // sorted pos -> filtered index
__device__ int    g_keptPos[N_ANCHORS];  // compact kept list (sorted positions, ascending)
__device__ int    g_F, g_K, g_np, g_done;
__device__ float  g_loss;

__device__ __forceinline__ unsigned long long shfl64(unsigned long long v, int l) {
    return __shfl(v, l, 64);
}

// key = conf[i][0] if max(conf[i][:]) > 0.5 else -1  (exact fmax tree/order preserved)
__device__ __forceinline__ float anchor_key(const float* __restrict__ conf, int i, bool& valid) {
    const float4* cp4 = (const float4*)(conf + (size_t)i * NUM_CLASSES);
    float4 v0 = cp4[0];
    float score = v0.x;
    float m = fmaxf(fmaxf(v0.x, v0.y), fmaxf(v0.z, v0.w));
    #pragma unroll
    for (int c = 1; c < NUM_CLASSES / 4; ++c) {
        float4 v = cp4[c];
        m = fmaxf(m, fmaxf(fmaxf(v.x, v.y), fmaxf(v.z, v.w)));
    }
    valid = m > 0.5f;
    return valid ? score : -1.0f;
}

// ---------------- K1: counting-sort rank partials (keys computed in-block from conf;
// no prep kernel, no atomics, no zero-init dependency) ----------------
// rank_i = #{valid j : key_j > key_i || (key_j == key_i && j < i)}  (stable desc sort)
// fic_i  = #{valid j : j < i}
__global__ void __launch_bounds__(256) k_rank(const float* __restrict__ conf) {
    __shared__ float skey[256];
    int y = blockIdx.y;
    int j0 = y * 256;
    bool vj;
    skey[threadIdx.x] = anchor_key(conf, j0 + threadIdx.x, vj);
    int i = blockIdx.x * 256 + threadIdx.x;
    bool vi;
    float ki = anchor_key(conf, i, vi);
    __syncthreads();
    int r = 0, f = 0;
    #pragma unroll 8
    for (int jj = 0; jj < 256; ++jj) {
        float kj = skey[jj];
        int j = j0 + jj;
        bool valid_j = kj >= 0.0f;
        r += (kj > ki) || (kj == ki && j < i && valid_j);
        f += (j < i) && valid_j;
    }
    g_rpart[y][i] = r;   // plain stores: unique (y,i) per thread
    g_fpart[y][i] = f;
}

// ---------------- K2: reduce partials + scatter into sorted order (+ F, boxes) ----------------
__global__ void __launch_bounds__(256) k_scatter(const float* __restrict__ loc,
                                                 const float* __restrict__ conf,
                                                 const float* __restrict__ tb) {
    int i = blockIdx.x * 256 + threadIdx.x;
    bool vi;
    float ki = anchor_key(conf, i, vi);
    (void)ki;
    int r = 0, f = 0;
    #pragma unroll
    for (int y = 0; y < NTILES; ++y) { r += g_rpart[y][i]; f += g_fpart[y][i]; }
    if (vi) {
        float px = loc[2 * i], py = loc[2 * i + 1];
        float4 b;
        b.x = __fmul_rn(tb[0], px);
        b.y = __fmul_rn(tb[1], py);
        b.z = __fmul_rn(tb[2], px);
        b.w = __fmul_rn(tb[3], py);
        g_sbox[r] = b;
        g_sAnchor[r] = i;
        g_sFi[r] = f;
    }
    if (i == N_ANCHORS - 1) g_F = f + (vi ? 1 : 0);   // total valid count, no atomic
}

// ---------------- K3: IoU > 0.5 bitmask, upper triangle (word >= row/64) ----------------
// NOTE: the __fdiv_rn must stay — predicate must be bit-identical to XLA's
// inter/union division; a mul-compare rewrite flips ~2 expected borderline
// pairs out of 18.9M (q in (0.5, 0.5*(1+2^-24)]) and changes the kept set.
__global__ void __launch_bounds__(256) k_mask(void) {
    int wave = (blockIdx.x * 256 + threadIdx.x) >> 6;
    int lane = threadIdx.x & 63;
    if (wave >= N_ANCHORS) return;
    int i = wave;
    float4 bi = g_sbox[i];
    float areai = __fmul_rn(bi.z - bi.x, bi.w - bi.y);
    unsigned long long* row = g_mask + (size_t)i * NWORDS;
    for (int w = (i >> 6); w < NWORDS; ++w) {
        float4 bj = g_sbox[w * 64 + lane];
        float areaj = __fmul_rn(bj.z - bj.x, bj.w - bj.y);
        float lx = fmaxf(bi.x, bj.x), ly = fmaxf(bi.y, bj.y);
        float rx = fminf(bi.z, bj.z), ry = fminf(bi.w, bj.w);
        float iw = fmaxf(rx - lx, 0.0f), ih = fmaxf(ry - ly, 0.0f);
        float inter = __fmul_rn(iw, ih);
        float denom = __fsub_rn(__fadd_rn(areai, areaj), inter);
        float iou = __fdiv_rn(inter, denom);
        unsigned long long bits = __ballot(iou > 0.5f);
        if (lane == 0) row[w] = bits;
    }
}

// ---------------- K4: single-wave greedy-NMS scan, GLOBAL candidate batching ----------------
// Suppression only shrinks the candidate set -> the first B unsuppressed positions
// under the CURRENT remv are a sound superset of the next B greedy decisions.
// B=32 halves sequential HBM round trips vs B=16 (measured waste was only 13%).
// __launch_bounds__(64,1): 1-wave kernel, no occupancy pressure -> full VGPR budget
// so r0[32]/r1[32] (128 VGPRs) stay in registers instead of scratch (r2: VGPR=56 => spilled).
#define SCAN_B 32
__global__ void __launch_bounds__(64, 1) k_scan(void) {
    int lane = threadIdx.x;
    int F = g_F;
    if (lane == 0) { g_loss = 0.0f; g_np = 0; g_done = 0; }   // consumed by k_loss next dispatch
    // remv word init: positions >= F pre-suppressed
    auto initw = [&](int w) -> unsigned long long {
        long long lo = (long long)w * 64, hi = lo + 64;
        if (F <= lo) return ~0ull;
        if (F >= hi) return 0ull;
        return (~0ull) << (F - lo);
    };
    unsigned long long remv0 = initw(lane);                                  // word lane
    unsigned long long remv1 = (lane < 32) ? initw(64 + lane) : ~0ull;       // word 64+lane
    unsigned long long kept0 = 0, kept1 = 0;
    int lastPos = -1;   // greedy decisions finalized for all positions <= lastPos

    __shared__ int slots[SCAN_B];

    while (true) {
        // --- extract first SCAN_B candidate positions > lastPos under current remv ---
        unsigned long long c0 = ~remv0;                       // word = lane
        unsigned long long c1 = (lane < 32) ? ~remv1 : 0ull;  // word = 64 + lane
        {
            long long lo = (long long)lane << 6;
            if (lastPos >= lo + 63)      c0 = 0ull;
            else if (lastPos >= lo)      c0 &= (~0ull) << (int)(lastPos - lo + 1);
        }
        if (lane < 32) {
            long long lo = (long long)(64 + lane) << 6;
            if (lastPos >= lo + 63)      c1 = 0ull;
            else if (lastPos >= lo)      c1 &= (~0ull) << (int)(lastPos - lo + 1);
        }
        int n0 = __popcll(c0), n1 = __popcll(c1);
        int x0 = n0, x1 = n1;
        for (int ofs = 1; ofs < 64; ofs <<= 1) {
            int y0 = __shfl_up(x0, ofs, 64);
            int y1 = __shfl_up(x1, ofs, 64);
            if (lane >= ofs) { x0 += y0; x1 += y1; }
        }
        int tot0 = __shfl(x0, 63, 64);
        int tot1 = __shfl(x1, 63, 64);     // n1 == 0 for lane >= 32, so lane63 holds full sum
        int total = tot0 + tot1;
        if (total == 0) break;
        int off0 = x0 - n0;
        int off1 = tot0 + (x1 - n1);
        {   // write the first SCAN_B candidate positions (global rank order) to LDS
            unsigned long long wd = c0; int r = off0;
            while (wd && r < SCAN_B) { int b = __builtin_ctzll(wd); slots[r++] = lane * 64 + b; wd &= wd - 1; }
        }
        if (lane < 32) {
            unsigned long long wd = c1; int r = off1;
            while (wd && r < SCAN_B) { int b = __builtin_ctzll(wd); slots[r++] = (64 + lane) * 64 + b; wd &= wd - 1; }
        }
        __syncthreads();   // lgkmcnt drain: LDS writes visible before uniform reads
        int nb = (total < SCAN_B) ? total : SCAN_B;
        int pos[SCAN_B];
        #pragma unroll
        for (int q = 0; q < SCAN_B; ++q) pos[q] = (q < nb) ? slots[q] : -1;
        __syncthreads();   // all lanes past the reads before next-iter writes

        // --- one fused round trip: load all candidate rows (96 words over 64 lanes) ---
        unsigned long long r0[SCAN_B], r1[SCAN_B];
        #pragma unroll
        for (int q = 0; q < SCAN_B; ++q) {
            if (pos[q] >= 0) {
                const unsigned long long* rp = g_mask + (size_t)pos[q] * NWORDS;
                r0[q] = rp[lane];
                r1[q] = (lane < 32) ? rp[64 + lane] : 0ull;
            } else { r0[q] = 0ull; r1[q] = 0ull; }
        }

        // --- sequential greedy resolve (wave-uniform decisions) ---
        #pragma unroll
        for (int q = 0; q < SCAN_B; ++q) {
            if (pos[q] >= 0) {
                int w = pos[q] >> 6, b = pos[q] & 63;
                unsigned long long cw = (w < 64) ? shfl64(remv0, w) : shfl64(remv1, w - 64);
                if (!((cw >> b) & 1ull)) {
                    // kept: fold its row into the distributed suppression state
                    remv0 |= r0[q];
                    if (lane < 32) remv1 |= r1[q];
                    if (w < 64) { if (lane == w) kept0 |= 1ull << b; }
                    else        { if (lane == w - 64) kept1 |= 1ull << b; }
                }
                lastPos = pos[q];
            }
        }
    }

    // compact kept list in sorted order
    int c0 = __popcll(kept0);
    int c1 = (lane < 32) ? __popcll(kept1) : 0;
    int x0 = c0, x1 = c1;
    for (int ofs = 1; ofs < 64; ofs <<= 1) {
        int y0 = __shfl_up(x0, ofs, 64);
        int y1 = __shfl_up(x1, ofs, 64);
        if (lane >= ofs) { x0 += y0; x1 += y1; }
    }
    int t0 = __shfl(x0, 63, 64);
    int t1 = __shfl(x1, 63, 64);
    int off = x0 - c0;
    unsigned long long wd = kept0;
    while (wd) { int b = __builtin_ctzll(wd); g_keptPos[off++] = lane * 64 + b; wd &= wd - 1; }
    off = t0 + (x1 - c1);
    wd = kept1;
    while (wd) { int b = __builtin_ctzll(wd); g_keptPos[off++] = (64 + lane) * 64 + b; wd &= wd - 1; }
    if (lane == 0) g_K = t0 + t1;
}

// ---------------- K5: per-class top-1 (ties -> first kept) + smooth-L1 + num_pos
//                      + fused finalize via last-block-done counter ----------------
// Cross-block/XCD traffic all via device-scope atomics at the coherent point
// (per-XCD L2s are not coherent; plain stores would be unsafe here).
__global__ void __launch_bounds__(64) k_loss(const float* __restrict__ conf, const float* __restrict__ tb,
                                             float* __restrict__ out) {
    int c = blockIdx.x;
    int lane = threadIdx.x;
    int K = g_K;
    float bv = -3.402823466e+38f;
    int bk = 0x7fffffff;
    int np = 0;
    for (int k = lane; k < K; k += 64) {
        int p = g_keptPos[k];
        int a = g_sAnchor[p];
        float v = conf[(size_t)a * NUM_CLASSES + c];
        if (v > bv || (v == bv && k < bk)) { bv = v; bk = k; }
        if (c == 0) np += g_sFi[p];
    }
    for (int ofs = 32; ofs > 0; ofs >>= 1) {
        float ov = __shfl_down(bv, ofs, 64);
        int ok = __shfl_down(bk, ofs, 64);
        if (ov > bv || (ov == bv && ok < bk)) { bv = ov; bk = ok; }
    }
    if (c == 0) {
        for (int ofs = 32; ofs > 0; ofs >>= 1) np += __shfl_down(np, ofs, 64);
        if (lane == 0) atomicExch(&g_np, np);   // device-scope write (cross-XCD reader)
    }
    if (lane == 0) {
        if (K > 0) {
            float4 b = g_sbox[g_keptPos[bk]];
            float t0 = tb[0], t1 = tb[1], t2 = tb[2], t3 = tb[3];
            float l = 0.0f, d;
            d = fabsf(b.x - t0); l += (d < 1.0f) ? 0.5f * d * d : d - 0.5f;
            d = fabsf(b.y - t1); l += (d < 1.0f) ? 0.5f * d * d : d - 0.5f;
            d = fabsf(b.z - t2); l += (d < 1.0f) ? 0.5f * d * d : d - 0.5f;
            d = fabsf(b.w - t3); l += (d < 1.0f) ? 0.5f * d * d : d - 0.5f;
            atomicAdd(&g_loss, l);
        }
        __threadfence();                          // order my atomics before the done-count
        int done = atomicAdd(&g_done, 1);
        if (done == NUM_CLASSES - 1) {            // last block finalizes (saves a launch)
            float total = atomicAdd(&g_loss, 0.0f);   // coherent-point read
            int npv = atomicAdd(&g_np, 0);            // coherent-point read
            out[0] = (g_F == 0 || K == 0) ? 0.001f : total / (float)npv;
        }
    }
}

extern "C" void kernel_launch(void* const* d_in, const int* in_sizes, int n_in,
                              void* d_out, int out_size, void* d_ws, size_t ws_size,
                              hipStream_t stream) {
    const float* loc  = (const float*)d_in[0];   // (1, 6144, 2)  f32
    const float* conf = (const float*)d_in[1];   // (1, 6144, 80) f32
    const float* tb   = (const float*)d_in[2];   // (1, 1, 4)     f32
    float* out = (float*)d_out;

    k_rank<<<dim3(NTILES, NTILES), 256, 0, stream>>>(conf);
    k_scatter<<<NTILES, 256, 0, stream>>>(loc, conf, tb);
    k_mask<<<(N_ANCHORS * 64) / 256, 256, 0, stream>>>();
    k_scan<<<1, 64, 0, stream>>>();
    k_loss<<<NUM_CLASSES, 64, 0, stream>>>(conf, tb, out);
}